// Round 1
// 266.544 us; speedup vs baseline: 1.0131x; 1.0131x over previous
//
#include <hip/hip_runtime.h>
#include <cmath>

typedef __attribute__((ext_vector_type(8))) short  short8;   // 8 bf16 = 4 VGPRs
typedef __attribute__((ext_vector_type(4))) float  float4v;  // 4 fp32 acc

constexpr int kB  = 8;
constexpr int kC  = 256;
constexpr int kCQ = 32;
constexpr int kN  = 4096;
constexpr int kE  = 320;
constexpr float kLog2e = 1.44269504088896340736f;
constexpr float kMfix  = 10.0f;   // fixed softmax max (R5-proven: s*log2e within ~±4)

// R7: hardware bf16 convert (RNE, same rounding as the old manual path).
__device__ __forceinline__ uint cvt_pk_bf16(float lo, float hi) {
    uint r;
    asm("v_cvt_pk_bf16_f32 %0, %1, %2" : "=v"(r) : "v"(lo), "v"(hi));
    return r;
}
__device__ __forceinline__ ushort f2bf(float f) {   // fp32 -> bf16 RNE, 1 VALU op
    return (ushort)cvt_pk_bf16(f, 0.0f);
}
__device__ __forceinline__ float bf2f(ushort h) {
    return __uint_as_float((uint)h << 16);
}

// ---------------------------------------------------------------------------
// Prep: pack wv|wq*log2e|wk into Wb[320][256] bf16, biases into bb[320] f32.
// ---------------------------------------------------------------------------
__global__ __launch_bounds__(256) void prep_kernel(
    const float* __restrict__ wq, const float* __restrict__ bq,
    const float* __restrict__ wk, const float* __restrict__ bk,
    const float* __restrict__ wv, const float* __restrict__ bv,
    ushort* __restrict__ Wb, float* __restrict__ bb)
{
    const int e = blockIdx.x;
    const int c = threadIdx.x;
    const float* src; float bsrc; float scale = 1.0f;
    if (e < 256)      { src = wv + (size_t)e * kC;        bsrc = bv[e]; }
    else if (e < 288) { src = wq + (size_t)(e-256) * kC;  bsrc = bq[e-256]; scale = kLog2e; }
    else              { src = wk + (size_t)(e-288) * kC;  bsrc = bk[e-288]; }
    Wb[(size_t)e * kC + c] = f2bf(src[c] * scale);
    if (c == 0) bb[e] = bsrc * scale;
}

// ---------------------------------------------------------------------------
// MFMA projection GEMM: D[e][n] = sum_c Wb[e][c]*x[b][c][n], e in [0,320).
// grid (128, 8), block 256 (4 waves), 4 blocks/CU.
// R6: epilogue repacked through LDS -> 16B coalesced stores.
// R7: staging + epilogue packs use v_cvt_pk_bf16_f32 (was ~5 VALU/val).
// ---------------------------------------------------------------------------
__global__ __launch_bounds__(256, 4) void proj_kernel(
    const float* __restrict__ x,
    const ushort* __restrict__ Wb, const float* __restrict__ bb,
    ushort* __restrict__ Qn, ushort* __restrict__ Kn, ushort* __restrict__ Vc)
{
    // union: phase1 = xF[32][264] (8448 us); phase2 = vreg[256][40] (10240 us)
    //        + Tq[32][72] (2304 us) at offset 10240.
    __shared__ __align__(16) ushort u_s[12544];   // 25.1 KB

    const int t    = threadIdx.x;
    const int b    = blockIdx.y;
    const int n0   = blockIdx.x * 32;
    const int lane = t & 63;
    const int w    = t >> 6;
    const int col  = lane & 15;
    const int quad = lane >> 4;

    // ---- stage x[b][0:256][n0:n0+32] -> xF[n][c] (bf16, transposed) ----
    {
        const int n4 = t & 7;
        const int cb = t >> 3;
#pragma unroll
        for (int r = 0; r < 2; ++r) {
            const int c0 = r * 128 + cb * 4;
            float4 L[4];
#pragma unroll
            for (int i = 0; i < 4; ++i)
                L[i] = *(const float4*)(x + ((size_t)b * kC + c0 + i) * kN + n0 + n4 * 4);
#pragma unroll
            for (int jj = 0; jj < 4; ++jj) {
                uint2 pk;
                pk.x = cvt_pk_bf16(((const float*)&L[0])[jj], ((const float*)&L[1])[jj]);
                pk.y = cvt_pk_bf16(((const float*)&L[2])[jj], ((const float*)&L[3])[jj]);
                *(uint2*)&u_s[(n4 * 4 + jj) * 264 + c0] = pk;
            }
        }
    }
    __syncthreads();

    float4v acc[5][2];
#pragma unroll
    for (int mt = 0; mt < 5; ++mt)
#pragma unroll
        for (int nt = 0; nt < 2; ++nt) acc[mt][nt] = float4v{0.f, 0.f, 0.f, 0.f};

    const ushort* ap[5];
#pragma unroll
    for (int mt = 0; mt < 5; ++mt)
        ap[mt] = Wb + ((size_t)(w * 80 + mt * 16 + col)) * kC + quad * 8;

#pragma unroll
    for (int kc = 0; kc < 8; ++kc) {
        short8 bf[2];
#pragma unroll
        for (int nt = 0; nt < 2; ++nt)
            bf[nt] = *(const short8*)&u_s[(nt * 16 + col) * 264 + kc * 32 + quad * 8];
#pragma unroll
        for (int mt = 0; mt < 5; ++mt) {
            const short8 af = *(const short8*)(ap[mt] + kc * 32);
#pragma unroll
            for (int nt = 0; nt < 2; ++nt)
                acc[mt][nt] = __builtin_amdgcn_mfma_f32_16x16x32_bf16(af, bf[nt], acc[mt][nt], 0, 0, 0);
        }
    }
    __syncthreads();   // xF dead; u_s becomes vreg/Tq

    // ---- epilogue: +bias -> LDS repack ----
#pragma unroll
    for (int mt = 0; mt < 5; ++mt) {
        const int e_t = w * 80 + mt * 16;
        const float4 b4 = *(const float4*)(bb + e_t + quad * 4);
#pragma unroll
        for (int nt = 0; nt < 2; ++nt) {
#pragma unroll
            for (int rr = 0; rr < 4; ++rr) {
                const int e = e_t + quad * 4 + rr;
                const ushort v = f2bf(acc[mt][nt][rr] + ((const float*)&b4)[rr]);
                if (e < 256) u_s[e * 40 + nt * 16 + col] = v;                      // vreg[e][n]
                else         u_s[10240 + (nt * 16 + col) * 72 + (e - 256)] = v;    // Tq[n][e']
            }
        }
    }
    __syncthreads();

    // ---- V stores: 1024 tasks of 16B (rows e, 8n chunks) ----
#pragma unroll
    for (int k = 0; k < 4; ++k) {
        const int task = k * 256 + t;
        const int row = task >> 2, chunk = task & 3;
        short8 v = *(const short8*)&u_s[row * 40 + chunk * 8];
        *(short8*)(Vc + ((size_t)b * kC + row) * kN + n0 + chunk * 8) = v;
    }
    // ---- Q/K stores: 256 tasks of 16B ----
    {
        const int n_l = t >> 3, chunk = t & 7;
        short8 v = *(const short8*)&u_s[10240 + n_l * 72 + chunk * 8];
        ushort* dst = (chunk < 4)
            ? (Qn + ((size_t)b * kN + n0 + n_l) * kCQ + chunk * 8)
            : (Kn + ((size_t)b * kN + n0 + n_l) * kCQ + (chunk - 4) * 8);
        *(short8*)dst = v;
    }
}

// ---------------------------------------------------------------------------
// MFMA flash attention, fixed-max softmax, in-block key-split.
// grid (64 qb, 8 b), block 512 (8 waves) -> 2 blocks/CU, 4 waves/SIMD.
// R7: software-pipelined P production. Per tile t: load K(t+1) + issue
// S(t+1)-MFMA, PV(t) half 1, exp2/cvt_pk(t+1) (hides under PV-MFMA issue),
// PV(t) half 2, write P(t+1) to the other buffer, one barrier.  This
// overlaps the VALU/trans softmax phase with the MFMA PV phase (previously
// barrier-separated -> pipes alternated: MfmaUtil 18%, VALUBusy 32%).
// Also: -kMfix folded into S-MFMA C-operand (kills 16 v_sub/tile);
// P pack via v_cvt_pk_bf16_f32 (was ~70 VALU/tile, now 8 ops).
// ---------------------------------------------------------------------------
__global__ __launch_bounds__(512, 4) void attn_kernel(
    const ushort* __restrict__ Qn, const ushort* __restrict__ Kn,
    const ushort* __restrict__ Vc,
    const float* __restrict__ x, const float* __restrict__ gptr,
    float* __restrict__ out)
{
    __shared__ __align__(16) ushort p_s[2][2][4608];   // [g][buf][64*72] 36.9 KB
    __shared__ float li_s[2][64];
    __shared__ float linv_s[64];

    const int t    = threadIdx.x;
    const int qb   = blockIdx.x;
    const int b    = blockIdx.y;
    const int w    = t >> 6;
    const int g    = w >> 2;      // key half
    const int wq   = w & 3;       // query/channel sub
    const int lane = t & 63;
    const int col  = lane & 15;
    const int quad = lane >> 4;
    const int cw   = wq * 64;

    const short8 qfrag = *(const short8*)(
        Qn + ((size_t)b * kN + qb * 64 + wq * 16 + col) * kCQ + quad * 8);

    const ushort* kp = Kn + ((size_t)b * kN + g * 2048 + col) * kCQ + quad * 8;
    const ushort* vp[4];
#pragma unroll
    for (int mt = 0; mt < 4; ++mt)
        vp[mt] = Vc + ((size_t)b * kC + cw + mt * 16 + col) * kN + g * 2048 + quad * 8;

    ushort* psg = &p_s[g][0][0];

    float4v acc[4][4];
#pragma unroll
    for (int mt = 0; mt < 4; ++mt)
#pragma unroll
        for (int nt = 0; nt < 4; ++nt) acc[mt][nt] = float4v{0.f, 0.f, 0.f, 0.f};
    float lsum = 0.f;
    const float4v mInit = {-kMfix, -kMfix, -kMfix, -kMfix};

    float4v s[4];
    uint    pk[8];

    // load current K tile, issue S^T = K·Q^T - M (C-operand carries -M)
    auto loadK_S = [&]() {
        short8 kf[4];
#pragma unroll
        for (int mt = 0; mt < 4; ++mt) kf[mt] = *(const short8*)(kp + mt * 512);
#pragma unroll
        for (int mt = 0; mt < 4; ++mt)
            s[mt] = __builtin_amdgcn_mfma_f32_16x16x32_bf16(kf[mt], qfrag, mInit, 0, 0, 0);
        kp += 2048;   // 64 keys * 32 us
    };
    // P = exp2(s); accumulate l; pack to bf16 pairs (8 regs carried)
    auto finishP = [&]() {
#pragma unroll
        for (int mt = 0; mt < 4; ++mt) {
            const float p0 = exp2f(s[mt][0]);
            const float p1 = exp2f(s[mt][1]);
            const float p2 = exp2f(s[mt][2]);
            const float p3 = exp2f(s[mt][3]);
            lsum += (p0 + p1) + (p2 + p3);
            pk[2 * mt]     = cvt_pk_bf16(p0, p1);
            pk[2 * mt + 1] = cvt_pk_bf16(p2, p3);
        }
    };
    auto writeP = [&](ushort* dst) {
        const int row_base = (wq * 16 + col) * 72;
#pragma unroll
        for (int mt = 0; mt < 4; ++mt) {
            uint2 wv2; wv2.x = pk[2 * mt]; wv2.y = pk[2 * mt + 1];
            *(uint2*)&dst[row_base + mt * 16 + quad * 4] = wv2;
        }
    };

    // ---- prologue: produce P(0) into buf0 ----
    loadK_S();
    finishP();
    writeP(psg);
    __syncthreads();

    // ---- pipelined main loop: consume P(t), produce P(t+1) ----
    for (int tile = 0; tile < 31; ++tile) {
        const int cur = (tile & 1) * 4608;
        const int nxt = 4608 - cur;

        loadK_S();                                   // K(t+1) + S(t+1) issue

        short8 vf[4], pf[4];
#pragma unroll
        for (int mt = 0; mt < 4; ++mt) vf[mt] = *(const short8*)(vp[mt]);
#pragma unroll
        for (int nt = 0; nt < 4; ++nt)
            pf[nt] = *(const short8*)&psg[cur + (nt * 16 + col) * 72 + quad * 8];
#pragma unroll
        for (int mt = 0; mt < 4; ++mt)
#pragma unroll
            for (int nt = 0; nt < 4; ++nt)
                acc[mt][nt] = __builtin_amdgcn_mfma_f32_16x16x32_bf16(vf[mt], pf[nt], acc[mt][nt], 0, 0, 0);

        finishP();                                   // exp/pack(t+1) under PV

#pragma unroll
        for (int mt = 0; mt < 4; ++mt) vf[mt] = *(const short8*)(vp[mt] + 32);
#pragma unroll
        for (int nt = 0; nt < 4; ++nt)
            pf[nt] = *(const short8*)&psg[cur + (nt * 16 + col) * 72 + 32 + quad * 8];
#pragma unroll
        for (int mt = 0; mt < 4; ++mt)
#pragma unroll
            for (int nt = 0; nt < 4; ++nt)
                acc[mt][nt] = __builtin_amdgcn_mfma_f32_16x16x32_bf16(vf[mt], pf[nt], acc[mt][nt], 0, 0, 0);
#pragma unroll
        for (int mt = 0; mt < 4; ++mt) vp[mt] += 64;

        writeP(psg + nxt);                           // P(t+1) -> other buffer
        __syncthreads();
    }

    // ---- tail: consume P(31) (buf1) ----
    {
        const int cur = 4608;
        short8 vf[4], pf[4];
#pragma unroll
        for (int mt = 0; mt < 4; ++mt) vf[mt] = *(const short8*)(vp[mt]);
#pragma unroll
        for (int nt = 0; nt < 4; ++nt)
            pf[nt] = *(const short8*)&psg[cur + (nt * 16 + col) * 72 + quad * 8];
#pragma unroll
        for (int mt = 0; mt < 4; ++mt)
#pragma unroll
            for (int nt = 0; nt < 4; ++nt)
                acc[mt][nt] = __builtin_amdgcn_mfma_f32_16x16x32_bf16(vf[mt], pf[nt], acc[mt][nt], 0, 0, 0);
#pragma unroll
        for (int mt = 0; mt < 4; ++mt) vf[mt] = *(const short8*)(vp[mt] + 32);
#pragma unroll
        for (int nt = 0; nt < 4; ++nt)
            pf[nt] = *(const short8*)&psg[cur + (nt * 16 + col) * 72 + 32 + quad * 8];
#pragma unroll
        for (int mt = 0; mt < 4; ++mt)
#pragma unroll
            for (int nt = 0; nt < 4; ++nt)
                acc[mt][nt] = __builtin_amdgcn_mfma_f32_16x16x32_bf16(vf[mt], pf[nt], acc[mt][nt], 0, 0, 0);
    }

    // ---- l partial ----
    lsum += __shfl_xor(lsum, 16);
    lsum += __shfl_xor(lsum, 32);
    __syncthreads();   // A: all p_s reads done
    if (quad == 0) li_s[g][wq * 16 + col] = lsum;

    ushort* scr = &p_s[0][0][0];
    // ---- group1 dumps acc (bf16), group0 sums ----
    if (g == 1) {
#pragma unroll
        for (int i = 0; i < 8; ++i) {
            const int mt = i >> 1, ntb = (i & 1) * 2;
            int4 v;
            v.x = (int)cvt_pk_bf16(acc[mt][ntb][0],     acc[mt][ntb][1]);
            v.y = (int)cvt_pk_bf16(acc[mt][ntb][2],     acc[mt][ntb][3]);
            v.z = (int)cvt_pk_bf16(acc[mt][ntb + 1][0], acc[mt][ntb + 1][1]);
            v.w = (int)cvt_pk_bf16(acc[mt][ntb + 1][2], acc[mt][ntb + 1][3]);
            *(int4*)&scr[wq * 4096 + i * 512 + lane * 8] = v;
        }
    }
    __syncthreads();   // B
    if (g == 0) {
#pragma unroll
        for (int i = 0; i < 8; ++i) {
            const int mt = i >> 1, ntb = (i & 1) * 2;
            short8 v = *(const short8*)&scr[wq * 4096 + i * 512 + lane * 8];
#pragma unroll
            for (int j = 0; j < 8; ++j)
                acc[mt][ntb + (j >> 2)][j & 3] += bf2f((ushort)v[j]);
        }
    }
    if (t < 64) linv_s[t] = 1.0f / (li_s[0][t] + li_s[1][t]);
    __syncthreads();   // C

    // ---- epilogue: LDS transpose (2 rounds of 32 ch/wave) + coalesced out ----
    const float gm = gptr[0];
#pragma unroll
    for (int rd = 0; rd < 2; ++rd) {
        if (g == 0) {
#pragma unroll
            for (int mt2 = 0; mt2 < 2; ++mt2) {
                const int mt = rd * 2 + mt2;
#pragma unroll
                for (int nt = 0; nt < 4; ++nt)
#pragma unroll
                    for (int r = 0; r < 4; ++r)
                        scr[wq * 2304 + (mt2 * 16 + quad * 4 + r) * 72 + nt * 16 + col]
                            = f2bf(acc[mt][nt][r]);
            }
        }
        __syncthreads();
#pragma unroll
        for (int k = 0; k < 2; ++k) {
            const int task = k * 512 + t;          // 1024 tasks: 4 ch-groups x 32 rows x 8 chunks
            const int wqt = task >> 8, row = (task >> 3) & 31, chunk = task & 7;
            const int ch = wqt * 64 + rd * 32 + row;
            short8 v = *(const short8*)&scr[wqt * 2304 + row * 72 + chunk * 8];
            const float4 li0 = *(const float4*)&linv_s[chunk * 8];
            const float4 li1 = *(const float4*)&linv_s[chunk * 8 + 4];
            const size_t idx = ((size_t)b * kC + ch) * kN + qb * 64 + chunk * 8;
            const float4 x0 = *(const float4*)&x[idx];
            const float4 x1 = *(const float4*)&x[idx + 4];
            float4 o0, o1;
            o0.x = gm * bf2f((ushort)v[0]) * li0.x + x0.x;
            o0.y = gm * bf2f((ushort)v[1]) * li0.y + x0.y;
            o0.z = gm * bf2f((ushort)v[2]) * li0.z + x0.z;
            o0.w = gm * bf2f((ushort)v[3]) * li0.w + x0.w;
            o1.x = gm * bf2f((ushort)v[4]) * li1.x + x1.x;
            o1.y = gm * bf2f((ushort)v[5]) * li1.y + x1.y;
            o1.z = gm * bf2f((ushort)v[6]) * li1.z + x1.z;
            o1.w = gm * bf2f((ushort)v[7]) * li1.w + x1.w;
            *(float4*)&out[idx]     = o0;
            *(float4*)&out[idx + 4] = o1;
        }
        __syncthreads();
    }
}

extern "C" void kernel_launch(void* const* d_in, const int* in_sizes, int n_in,
                              void* d_out, int out_size, void* d_ws, size_t ws_size,
                              hipStream_t stream)
{
    const float* x  = (const float*)d_in[0];
    const float* wq = (const float*)d_in[1];
    const float* bq = (const float*)d_in[2];
    const float* wk = (const float*)d_in[3];
    const float* bk = (const float*)d_in[4];
    const float* wv = (const float*)d_in[5];
    const float* bv = (const float*)d_in[6];
    const float* gm = (const float*)d_in[7];
    float* out = (float*)d_out;

    ushort* Qn = (ushort*)d_ws;                         // [8][4096][32] bf16, 2 MB
    ushort* Kn = Qn + (size_t)kB * kN * kCQ;            // [8][4096][32] bf16, 2 MB
    ushort* Vc = Kn + (size_t)kB * kN * kCQ;            // [8][256][4096] bf16, 16 MB
    ushort* Wb = Vc + (size_t)kB * kC * kN;             // [320][256] bf16, 160 KB
    float*  bb = (float*)(Wb + (size_t)kE * kC);        // [320] f32

    prep_kernel<<<dim3(kE), 256, 0, stream>>>(wq, bq, wk, bk, wv, bv, Wb, bb);
    proj_kernel<<<dim3(128, 8), 256, 0, stream>>>(x, Wb, bb, Qn, Kn, Vc);
    attn_kernel<<<dim3(64, 8), 512, 0, stream>>>(Qn, Kn, Vc, x, gm, out);
}

// Round 2
// 263.717 us; speedup vs baseline: 1.0240x; 1.0107x over previous
//
#include <hip/hip_runtime.h>
#include <cmath>

typedef __attribute__((ext_vector_type(8))) short  short8;   // 8 bf16 = 4 VGPRs
typedef __attribute__((ext_vector_type(4))) float  float4v;  // 4 fp32 acc

constexpr int kB  = 8;
constexpr int kC  = 256;
constexpr int kCQ = 32;
constexpr int kN  = 4096;
constexpr int kE  = 320;
constexpr float kLog2e = 1.44269504088896340736f;
constexpr float kMfix  = 10.0f;   // fixed softmax max (R5-proven: s*log2e within ~±4)

// R7: hardware bf16 convert (RNE, same rounding as the old manual path).
__device__ __forceinline__ uint cvt_pk_bf16(float lo, float hi) {
    uint r;
    asm("v_cvt_pk_bf16_f32 %0, %1, %2" : "=v"(r) : "v"(lo), "v"(hi));
    return r;
}
__device__ __forceinline__ ushort f2bf(float f) {   // fp32 -> bf16 RNE, 1 VALU op
    return (ushort)cvt_pk_bf16(f, 0.0f);
}
__device__ __forceinline__ float bf2f(ushort h) {
    return __uint_as_float((uint)h << 16);
}

// ---------------------------------------------------------------------------
// Prep: pack wv|wq*log2e|wk into Wb[320][256] bf16, biases into bb[320] f32.
// ---------------------------------------------------------------------------
__global__ __launch_bounds__(256) void prep_kernel(
    const float* __restrict__ wq, const float* __restrict__ bq,
    const float* __restrict__ wk, const float* __restrict__ bk,
    const float* __restrict__ wv, const float* __restrict__ bv,
    ushort* __restrict__ Wb, float* __restrict__ bb)
{
    const int e = blockIdx.x;
    const int c = threadIdx.x;
    const float* src; float bsrc; float scale = 1.0f;
    if (e < 256)      { src = wv + (size_t)e * kC;        bsrc = bv[e]; }
    else if (e < 288) { src = wq + (size_t)(e-256) * kC;  bsrc = bq[e-256]; scale = kLog2e; }
    else              { src = wk + (size_t)(e-288) * kC;  bsrc = bk[e-288]; }
    Wb[(size_t)e * kC + c] = f2bf(src[c] * scale);
    if (c == 0) bb[e] = bsrc * scale;
}

// ---------------------------------------------------------------------------
// MFMA projection GEMM: D[e][n] = sum_c Wb[e][c]*x[b][c][n], e in [0,320).
// grid (128, 8), block 256 (4 waves), 4 blocks/CU.
// R6: epilogue repacked through LDS -> 16B coalesced stores.
// R7: staging + epilogue packs use v_cvt_pk_bf16_f32 (was ~5 VALU/val).
// ---------------------------------------------------------------------------
__global__ __launch_bounds__(256, 4) void proj_kernel(
    const float* __restrict__ x,
    const ushort* __restrict__ Wb, const float* __restrict__ bb,
    ushort* __restrict__ Qn, ushort* __restrict__ Kn, ushort* __restrict__ Vc)
{
    // union: phase1 = xF[32][264] (8448 us); phase2 = vreg[256][40] (10240 us)
    //        + Tq[32][72] (2304 us) at offset 10240.
    __shared__ __align__(16) ushort u_s[12544];   // 25.1 KB

    const int t    = threadIdx.x;
    const int b    = blockIdx.y;
    const int n0   = blockIdx.x * 32;
    const int lane = t & 63;
    const int w    = t >> 6;
    const int col  = lane & 15;
    const int quad = lane >> 4;

    // ---- stage x[b][0:256][n0:n0+32] -> xF[n][c] (bf16, transposed) ----
    {
        const int n4 = t & 7;
        const int cb = t >> 3;
#pragma unroll
        for (int r = 0; r < 2; ++r) {
            const int c0 = r * 128 + cb * 4;
            float4 L[4];
#pragma unroll
            for (int i = 0; i < 4; ++i)
                L[i] = *(const float4*)(x + ((size_t)b * kC + c0 + i) * kN + n0 + n4 * 4);
#pragma unroll
            for (int jj = 0; jj < 4; ++jj) {
                uint2 pk;
                pk.x = cvt_pk_bf16(((const float*)&L[0])[jj], ((const float*)&L[1])[jj]);
                pk.y = cvt_pk_bf16(((const float*)&L[2])[jj], ((const float*)&L[3])[jj]);
                *(uint2*)&u_s[(n4 * 4 + jj) * 264 + c0] = pk;
            }
        }
    }
    __syncthreads();

    float4v acc[5][2];
#pragma unroll
    for (int mt = 0; mt < 5; ++mt)
#pragma unroll
        for (int nt = 0; nt < 2; ++nt) acc[mt][nt] = float4v{0.f, 0.f, 0.f, 0.f};

    const ushort* ap[5];
#pragma unroll
    for (int mt = 0; mt < 5; ++mt)
        ap[mt] = Wb + ((size_t)(w * 80 + mt * 16 + col)) * kC + quad * 8;

#pragma unroll
    for (int kc = 0; kc < 8; ++kc) {
        short8 bf[2];
#pragma unroll
        for (int nt = 0; nt < 2; ++nt)
            bf[nt] = *(const short8*)&u_s[(nt * 16 + col) * 264 + kc * 32 + quad * 8];
#pragma unroll
        for (int mt = 0; mt < 5; ++mt) {
            const short8 af = *(const short8*)(ap[mt] + kc * 32);
#pragma unroll
            for (int nt = 0; nt < 2; ++nt)
                acc[mt][nt] = __builtin_amdgcn_mfma_f32_16x16x32_bf16(af, bf[nt], acc[mt][nt], 0, 0, 0);
        }
    }
    __syncthreads();   // xF dead; u_s becomes vreg/Tq

    // ---- epilogue: +bias -> LDS repack ----
#pragma unroll
    for (int mt = 0; mt < 5; ++mt) {
        const int e_t = w * 80 + mt * 16;
        const float4 b4 = *(const float4*)(bb + e_t + quad * 4);
#pragma unroll
        for (int nt = 0; nt < 2; ++nt) {
#pragma unroll
            for (int rr = 0; rr < 4; ++rr) {
                const int e = e_t + quad * 4 + rr;
                const ushort v = f2bf(acc[mt][nt][rr] + ((const float*)&b4)[rr]);
                if (e < 256) u_s[e * 40 + nt * 16 + col] = v;                      // vreg[e][n]
                else         u_s[10240 + (nt * 16 + col) * 72 + (e - 256)] = v;    // Tq[n][e']
            }
        }
    }
    __syncthreads();

    // ---- V stores: 1024 tasks of 16B (rows e, 8n chunks) ----
#pragma unroll
    for (int k = 0; k < 4; ++k) {
        const int task = k * 256 + t;
        const int row = task >> 2, chunk = task & 3;
        short8 v = *(const short8*)&u_s[row * 40 + chunk * 8];
        *(short8*)(Vc + ((size_t)b * kC + row) * kN + n0 + chunk * 8) = v;
    }
    // ---- Q/K stores: 256 tasks of 16B ----
    {
        const int n_l = t >> 3, chunk = t & 7;
        short8 v = *(const short8*)&u_s[10240 + n_l * 72 + chunk * 8];
        ushort* dst = (chunk < 4)
            ? (Qn + ((size_t)b * kN + n0 + n_l) * kCQ + chunk * 8)
            : (Kn + ((size_t)b * kN + n0 + n_l) * kCQ + (chunk - 4) * 8);
        *(short8*)dst = v;
    }
}

// ---------------------------------------------------------------------------
// MFMA flash attention, fixed-max softmax, in-block key-split.
// grid flat 512 blocks, block 512 (8 waves) -> 2 blocks/CU, 4 waves/SIMD.
// R8: XCD-affinity block remap. b = bid%8 puts all 64 qb-blocks of one batch
// on ONE XCD (dispatch round-robins linear id across 8 XCDs). Per-XCD
// main-loop working set drops 18MB -> ~2.5MB (< 4MB L2), so the V stream
// (128 KB/CU/tile, previously served at ~11.5 B/cyc/CU = L3 rate) becomes
// L2-hit (~56 B/cyc/CU). Correct regardless of the actual XCD mapping.
// R7: software-pipelined P production (exp/cvt_pk under PV-MFMA), -kMfix
// folded into S-MFMA C-operand, P pack via v_cvt_pk_bf16_f32.
// ---------------------------------------------------------------------------
__global__ __launch_bounds__(512, 4) void attn_kernel(
    const ushort* __restrict__ Qn, const ushort* __restrict__ Kn,
    const ushort* __restrict__ Vc,
    const float* __restrict__ x, const float* __restrict__ gptr,
    float* __restrict__ out)
{
    __shared__ __align__(16) ushort p_s[2][2][4608];   // [g][buf][64*72] 36.9 KB
    __shared__ float li_s[2][64];
    __shared__ float linv_s[64];

    const int t    = threadIdx.x;
    // R8: XCD-affinity remap (grid is flat 512 = 64 qb x 8 b)
    const int bid  = blockIdx.x;
    const int b    = bid & 7;     // XCD id under round-robin dispatch
    const int qb   = bid >> 3;
    const int w    = t >> 6;
    const int g    = w >> 2;      // key half
    const int wq   = w & 3;       // query/channel sub
    const int lane = t & 63;
    const int col  = lane & 15;
    const int quad = lane >> 4;
    const int cw   = wq * 64;

    const short8 qfrag = *(const short8*)(
        Qn + ((size_t)b * kN + qb * 64 + wq * 16 + col) * kCQ + quad * 8);

    const ushort* kp = Kn + ((size_t)b * kN + g * 2048 + col) * kCQ + quad * 8;
    const ushort* vp[4];
#pragma unroll
    for (int mt = 0; mt < 4; ++mt)
        vp[mt] = Vc + ((size_t)b * kC + cw + mt * 16 + col) * kN + g * 2048 + quad * 8;

    ushort* psg = &p_s[g][0][0];

    float4v acc[4][4];
#pragma unroll
    for (int mt = 0; mt < 4; ++mt)
#pragma unroll
        for (int nt = 0; nt < 4; ++nt) acc[mt][nt] = float4v{0.f, 0.f, 0.f, 0.f};
    float lsum = 0.f;
    const float4v mInit = {-kMfix, -kMfix, -kMfix, -kMfix};

    float4v s[4];
    uint    pk[8];

    // load current K tile, issue S^T = K·Q^T - M (C-operand carries -M)
    auto loadK_S = [&]() {
        short8 kf[4];
#pragma unroll
        for (int mt = 0; mt < 4; ++mt) kf[mt] = *(const short8*)(kp + mt * 512);
#pragma unroll
        for (int mt = 0; mt < 4; ++mt)
            s[mt] = __builtin_amdgcn_mfma_f32_16x16x32_bf16(kf[mt], qfrag, mInit, 0, 0, 0);
        kp += 2048;   // 64 keys * 32 us
    };
    // P = exp2(s); accumulate l; pack to bf16 pairs (8 regs carried)
    auto finishP = [&]() {
#pragma unroll
        for (int mt = 0; mt < 4; ++mt) {
            const float p0 = exp2f(s[mt][0]);
            const float p1 = exp2f(s[mt][1]);
            const float p2 = exp2f(s[mt][2]);
            const float p3 = exp2f(s[mt][3]);
            lsum += (p0 + p1) + (p2 + p3);
            pk[2 * mt]     = cvt_pk_bf16(p0, p1);
            pk[2 * mt + 1] = cvt_pk_bf16(p2, p3);
        }
    };
    auto writeP = [&](ushort* dst) {
        const int row_base = (wq * 16 + col) * 72;
#pragma unroll
        for (int mt = 0; mt < 4; ++mt) {
            uint2 wv2; wv2.x = pk[2 * mt]; wv2.y = pk[2 * mt + 1];
            *(uint2*)&dst[row_base + mt * 16 + quad * 4] = wv2;
        }
    };

    // ---- prologue: produce P(0) into buf0 ----
    loadK_S();
    finishP();
    writeP(psg);
    __syncthreads();

    // ---- pipelined main loop: consume P(t), produce P(t+1) ----
    for (int tile = 0; tile < 31; ++tile) {
        const int cur = (tile & 1) * 4608;
        const int nxt = 4608 - cur;

        loadK_S();                                   // K(t+1) + S(t+1) issue

        short8 vf[4], pf[4];
#pragma unroll
        for (int mt = 0; mt < 4; ++mt) vf[mt] = *(const short8*)(vp[mt]);
#pragma unroll
        for (int nt = 0; nt < 4; ++nt)
            pf[nt] = *(const short8*)&psg[cur + (nt * 16 + col) * 72 + quad * 8];
#pragma unroll
        for (int mt = 0; mt < 4; ++mt)
#pragma unroll
            for (int nt = 0; nt < 4; ++nt)
                acc[mt][nt] = __builtin_amdgcn_mfma_f32_16x16x32_bf16(vf[mt], pf[nt], acc[mt][nt], 0, 0, 0);

        finishP();                                   // exp/pack(t+1) under PV

#pragma unroll
        for (int mt = 0; mt < 4; ++mt) vf[mt] = *(const short8*)(vp[mt] + 32);
#pragma unroll
        for (int nt = 0; nt < 4; ++nt)
            pf[nt] = *(const short8*)&psg[cur + (nt * 16 + col) * 72 + 32 + quad * 8];
#pragma unroll
        for (int mt = 0; mt < 4; ++mt)
#pragma unroll
            for (int nt = 0; nt < 4; ++nt)
                acc[mt][nt] = __builtin_amdgcn_mfma_f32_16x16x32_bf16(vf[mt], pf[nt], acc[mt][nt], 0, 0, 0);
#pragma unroll
        for (int mt = 0; mt < 4; ++mt) vp[mt] += 64;

        writeP(psg + nxt);                           // P(t+1) -> other buffer
        __syncthreads();
    }

    // ---- tail: consume P(31) (buf1) ----
    {
        const int cur = 4608;
        short8 vf[4], pf[4];
#pragma unroll
        for (int mt = 0; mt < 4; ++mt) vf[mt] = *(const short8*)(vp[mt]);
#pragma unroll
        for (int nt = 0; nt < 4; ++nt)
            pf[nt] = *(const short8*)&psg[cur + (nt * 16 + col) * 72 + quad * 8];
#pragma unroll
        for (int mt = 0; mt < 4; ++mt)
#pragma unroll
            for (int nt = 0; nt < 4; ++nt)
                acc[mt][nt] = __builtin_amdgcn_mfma_f32_16x16x32_bf16(vf[mt], pf[nt], acc[mt][nt], 0, 0, 0);
#pragma unroll
        for (int mt = 0; mt < 4; ++mt) vf[mt] = *(const short8*)(vp[mt] + 32);
#pragma unroll
        for (int nt = 0; nt < 4; ++nt)
            pf[nt] = *(const short8*)&psg[cur + (nt * 16 + col) * 72 + 32 + quad * 8];
#pragma unroll
        for (int mt = 0; mt < 4; ++mt)
#pragma unroll
            for (int nt = 0; nt < 4; ++nt)
                acc[mt][nt] = __builtin_amdgcn_mfma_f32_16x16x32_bf16(vf[mt], pf[nt], acc[mt][nt], 0, 0, 0);
    }

    // ---- l partial ----
    lsum += __shfl_xor(lsum, 16);
    lsum += __shfl_xor(lsum, 32);
    __syncthreads();   // A: all p_s reads done
    if (quad == 0) li_s[g][wq * 16 + col] = lsum;

    ushort* scr = &p_s[0][0][0];
    // ---- group1 dumps acc (bf16), group0 sums ----
    if (g == 1) {
#pragma unroll
        for (int i = 0; i < 8; ++i) {
            const int mt = i >> 1, ntb = (i & 1) * 2;
            int4 v;
            v.x = (int)cvt_pk_bf16(acc[mt][ntb][0],     acc[mt][ntb][1]);
            v.y = (int)cvt_pk_bf16(acc[mt][ntb][2],     acc[mt][ntb][3]);
            v.z = (int)cvt_pk_bf16(acc[mt][ntb + 1][0], acc[mt][ntb + 1][1]);
            v.w = (int)cvt_pk_bf16(acc[mt][ntb + 1][2], acc[mt][ntb + 1][3]);
            *(int4*)&scr[wq * 4096 + i * 512 + lane * 8] = v;
        }
    }
    __syncthreads();   // B
    if (g == 0) {
#pragma unroll
        for (int i = 0; i < 8; ++i) {
            const int mt = i >> 1, ntb = (i & 1) * 2;
            short8 v = *(const short8*)&scr[wq * 4096 + i * 512 + lane * 8];
#pragma unroll
            for (int j = 0; j < 8; ++j)
                acc[mt][ntb + (j >> 2)][j & 3] += bf2f((ushort)v[j]);
        }
    }
    if (t < 64) linv_s[t] = 1.0f / (li_s[0][t] + li_s[1][t]);
    __syncthreads();   // C

    // ---- epilogue: LDS transpose (2 rounds of 32 ch/wave) + coalesced out ----
    const float gm = gptr[0];
#pragma unroll
    for (int rd = 0; rd < 2; ++rd) {
        if (g == 0) {
#pragma unroll
            for (int mt2 = 0; mt2 < 2; ++mt2) {
                const int mt = rd * 2 + mt2;
#pragma unroll
                for (int nt = 0; nt < 4; ++nt)
#pragma unroll
                    for (int r = 0; r < 4; ++r)
                        scr[wq * 2304 + (mt2 * 16 + quad * 4 + r) * 72 + nt * 16 + col]
                            = f2bf(acc[mt][nt][r]);
            }
        }
        __syncthreads();
#pragma unroll
        for (int k = 0; k < 2; ++k) {
            const int task = k * 512 + t;          // 1024 tasks: 4 ch-groups x 32 rows x 8 chunks
            const int wqt = task >> 8, row = (task >> 3) & 31, chunk = task & 7;
            const int ch = wqt * 64 + rd * 32 + row;
            short8 v = *(const short8*)&scr[wqt * 2304 + row * 72 + chunk * 8];
            const float4 li0 = *(const float4*)&linv_s[chunk * 8];
            const float4 li1 = *(const float4*)&linv_s[chunk * 8 + 4];
            const size_t idx = ((size_t)b * kC + ch) * kN + qb * 64 + chunk * 8;
            const float4 x0 = *(const float4*)&x[idx];
            const float4 x1 = *(const float4*)&x[idx + 4];
            float4 o0, o1;
            o0.x = gm * bf2f((ushort)v[0]) * li0.x + x0.x;
            o0.y = gm * bf2f((ushort)v[1]) * li0.y + x0.y;
            o0.z = gm * bf2f((ushort)v[2]) * li0.z + x0.z;
            o0.w = gm * bf2f((ushort)v[3]) * li0.w + x0.w;
            o1.x = gm * bf2f((ushort)v[4]) * li1.x + x1.x;
            o1.y = gm * bf2f((ushort)v[5]) * li1.y + x1.y;
            o1.z = gm * bf2f((ushort)v[6]) * li1.z + x1.z;
            o1.w = gm * bf2f((ushort)v[7]) * li1.w + x1.w;
            *(float4*)&out[idx]     = o0;
            *(float4*)&out[idx + 4] = o1;
        }
        __syncthreads();
    }
}

extern "C" void kernel_launch(void* const* d_in, const int* in_sizes, int n_in,
                              void* d_out, int out_size, void* d_ws, size_t ws_size,
                              hipStream_t stream)
{
    const float* x  = (const float*)d_in[0];
    const float* wq = (const float*)d_in[1];
    const float* bq = (const float*)d_in[2];
    const float* wk = (const float*)d_in[3];
    const float* bk = (const float*)d_in[4];
    const float* wv = (const float*)d_in[5];
    const float* bv = (const float*)d_in[6];
    const float* gm = (const float*)d_in[7];
    float* out = (float*)d_out;

    ushort* Qn = (ushort*)d_ws;                         // [8][4096][32] bf16, 2 MB
    ushort* Kn = Qn + (size_t)kB * kN * kCQ;            // [8][4096][32] bf16, 2 MB
    ushort* Vc = Kn + (size_t)kB * kN * kCQ;            // [8][256][4096] bf16, 16 MB
    ushort* Wb = Vc + (size_t)kB * kC * kN;             // [320][256] bf16, 160 KB
    float*  bb = (float*)(Wb + (size_t)kE * kC);        // [320] f32

    prep_kernel<<<dim3(kE), 256, 0, stream>>>(wq, bq, wk, bk, wv, bv, Wb, bb);
    proj_kernel<<<dim3(128, 8), 256, 0, stream>>>(x, Wb, bb, Qn, Kn, Vc);
    // R8: flat grid for XCD-affinity remap inside the kernel
    attn_kernel<<<dim3(512), 512, 0, stream>>>(Qn, Kn, Vc, x, gm, out);
}